// Round 14
// baseline (209.881 us; speedup 1.0000x reference)
//
#include <hip/hip_runtime.h>
#include <hip/hip_bf16.h>

// R19: attn = KVBLK=128 (R14's halved barrier events) + R11-EXACT staging
// geometry (row=tid>>2, col=(tid&3)*16, paired +0/+8 writes -- measured 0
// conflicts; R14's kr=tid>>1/dc=*32 geometry caused its 524K conflicts) +
// R18's unconditional distance-1 prefetch ((it+1)&3 wrap, branch-free).
// Four staging passes: K rows 0-63 / 64-127, V s-cols 0-63 / 64-127.
// proj: R18 form (BK=128, rule-21 swizzle). prep: R15 form. Both frozen.

typedef __bf16 bf16;
typedef bf16 bf16x8 __attribute__((ext_vector_type(8)));
typedef bf16 bf16x4 __attribute__((ext_vector_type(4)));
typedef float floatx4 __attribute__((ext_vector_type(4)));
typedef float floatx16 __attribute__((ext_vector_type(16)));
typedef unsigned short ushort8 __attribute__((ext_vector_type(8)));
typedef unsigned long long u64;

#define MFMA32(A, B, C)    __builtin_amdgcn_mfma_f32_16x16x32_bf16((A), (B), (C), 0, 0, 0)
#define MFMA32x32(A, B, C) __builtin_amdgcn_mfma_f32_32x32x16_bf16((A), (B), (C), 0, 0, 0)

namespace {
constexpr int S    = 512;
constexpr int H    = 16;
constexpr int Dh   = 64;
constexpr int D    = 1024;
constexpr int LDT  = 72;                         // K-tile row stride (bf16)
constexpr int LDTV = 136;                        // V-tile row stride (bf16)
constexpr size_t QN = (size_t)16 * S * H * Dh;   // 8,388,608
constexpr size_t WN = (size_t)D * D;             // 1,048,576
}

__device__ __forceinline__ float fexp2(float x) {
#if defined(__HIP_DEVICE_COMPILE__) && __has_builtin(__builtin_amdgcn_exp2f)
    return __builtin_amdgcn_exp2f(x);
#else
    return exp2f(x);
#endif
}

__device__ __forceinline__ int sbfe1(unsigned bits, int bit) {
    return ((int)(bits << (31 - bit))) >> 31;    // folds to v_bfe_i32
}

// Async global->LDS, 16B per lane. lds base must be wave-uniform (HW adds lane*16).
__device__ __forceinline__ void gload16(const bf16* g, bf16* ldsbase, int lane) {
#if __has_builtin(__builtin_amdgcn_global_load_lds)
    __builtin_amdgcn_global_load_lds(
        (__attribute__((address_space(1))) void*)(g),
        (__attribute__((address_space(3))) void*)(ldsbase), 16, 0, 0);
#else
    *(ushort8*)(ldsbase + lane * 8) = *(const ushort8*)g;   // host-pass / fallback
#endif
}

// Fused prep, grid 4352:
// [0,1024) K f32->bf16 x4 chunks | [1024,3072) V transpose | [3072,3328) W
// transpose | [3328,4352) mask bit-pack x4 units.
__global__ __launch_bounds__(256)
void prep_kernel(const float* __restrict__ Kf, const float* __restrict__ Vf,
                 const float* __restrict__ Wf, const int* __restrict__ Mg,
                 bf16* __restrict__ Kc, bf16* __restrict__ Vt,
                 bf16* __restrict__ Wt, u64* __restrict__ MB)
{
    __shared__ bf16 Ts[64 * LDT];
    const int blk = blockIdx.x, tid = threadIdx.x;

    if (blk < 1024) {                       // ---- K convert, 4 chunks/thread ----
        const int c0 = blk * 1024 + tid;    // chunk ids c0 + 256*k
        floatx4 f[4][2];
#pragma unroll
        for (int k = 0; k < 4; ++k) {
            const float* fs = Kf + (size_t)(c0 + k * 256) * 8;
            f[k][0] = *(const floatx4*)fs;
            f[k][1] = *(const floatx4*)(fs + 4);
        }
#pragma unroll
        for (int k = 0; k < 4; ++k) {
            bf16x8 v;
#pragma unroll
            for (int j = 0; j < 4; ++j) {
                v[j]     = (bf16)f[k][0][j];
                v[j + 4] = (bf16)f[k][1][j];
            }
            *(bf16x8*)(Kc + (size_t)(c0 + k * 256) * 8) = v;
        }
    } else if (blk < 3072) {                // ---- V [b][s][h][d] -> [(bh)][d][s] ----
        const int bk2 = blk - 1024;
        const int bh  = bk2 >> 3, st = bk2 & 7;
        const int b   = bh >> 4, h = bh & 15;
        const int r   = tid >> 2, c = (tid & 3) * 16;
        const float* src = Vf + ((size_t)((b * S + st * 64 + r) * H + h)) * Dh + c;
        floatx4 f0 = *(const floatx4*)src;          // vectorized: 4x dwordx4
        floatx4 f1 = *(const floatx4*)(src + 4);
        floatx4 f2 = *(const floatx4*)(src + 8);
        floatx4 f3 = *(const floatx4*)(src + 12);
        // element (d,s) stored at d*LDT + (s ^ (d&48)): write conflicts 8->2-way
#pragma unroll
        for (int i = 0; i < 4; ++i) {
            Ts[(c + i)      * LDT + (r ^ ((c + i)      & 48))] = (bf16)f0[i];
            Ts[(c + 4 + i)  * LDT + (r ^ ((c + 4 + i)  & 48))] = (bf16)f1[i];
            Ts[(c + 8 + i)  * LDT + (r ^ ((c + 8 + i)  & 48))] = (bf16)f2[i];
            Ts[(c + 12 + i) * LDT + (r ^ ((c + 12 + i) & 48))] = (bf16)f3[i];
        }
        __syncthreads();
        bf16* dst = Vt + ((size_t)bh * 64 + r) * S + st * 64 + c;
        const int rb = r * LDT + (c ^ (r & 48));
        *(ushort8*)dst       = *(const ushort8*)&Ts[rb];
        *(ushort8*)(dst + 8) = *(const ushort8*)&Ts[rb + 8];
    } else if (blk < 3328) {                // ---- W [k][n] -> [n][k] ----
        const int bk2 = blk - 3072;
        const int nb  = bk2 & 15, kb = bk2 >> 4;
        const int r   = tid >> 2, c = (tid & 3) * 16;
        const float* src = Wf + (size_t)(kb * 64 + r) * D + nb * 64 + c;
        floatx4 f0 = *(const floatx4*)src;          // vectorized: 4x dwordx4
        floatx4 f1 = *(const floatx4*)(src + 4);
        floatx4 f2 = *(const floatx4*)(src + 8);
        floatx4 f3 = *(const floatx4*)(src + 12);
#pragma unroll
        for (int i = 0; i < 4; ++i) {
            Ts[(c + i)      * LDT + (r ^ ((c + i)      & 48))] = (bf16)f0[i];
            Ts[(c + 4 + i)  * LDT + (r ^ ((c + 4 + i)  & 48))] = (bf16)f1[i];
            Ts[(c + 8 + i)  * LDT + (r ^ ((c + 8 + i)  & 48))] = (bf16)f2[i];
            Ts[(c + 12 + i) * LDT + (r ^ ((c + 12 + i) & 48))] = (bf16)f3[i];
        }
        __syncthreads();
        bf16* dst = Wt + (size_t)(nb * 64 + r) * D + kb * 64 + c;
        const int rb = r * LDT + (c ^ (r & 48));
        *(ushort8*)dst       = *(const ushort8*)&Ts[rb];
        *(ushort8*)(dst + 8) = *(const ushort8*)&Ts[rb + 8];
    } else {                                // ---- mask -> u64 bitmask, 4 units/wave ----
        const int bk2  = blk - 3328;        // [0,1024)
        const int lane = tid & 63;
        const int wv   = tid >> 6;
        const int u0   = bk2 * 16 + wv * 4; // idx4 base
        int mv[4][4];
#pragma unroll
        for (int u = 0; u < 4; ++u) {
            const int idx4 = u0 + u;
            const int row = idx4 >> 1, hf = idx4 & 1;
#pragma unroll
            for (int r = 0; r < 4; ++r)
                mv[u][r] = Mg[(size_t)row * 512 + hf * 256 + r * 64 + lane];
        }
#pragma unroll
        for (int u = 0; u < 4; ++u) {
            const int idx4 = u0 + u;
            const int row = idx4 >> 1, hf = idx4 & 1;
#pragma unroll
            for (int r = 0; r < 4; ++r) {
                u64 bm = __ballot(mv[u][r] != 0);
                if (lane == 0) MB[(size_t)row * 8 + hf * 4 + r] = bm;
            }
        }
    }
}

// One workgroup = one (b, h, 128-row q-tile). 4 waves x 32 q each (q = qw + l31).
// KVBLK=128 (4 iterations, 8 barriers) + unconditional distance-1 prefetch.
// Staging geometry = R11-exact (row=tid>>2, col=(tid&3)*16, +0/+8 pairs) x4 passes.
// S^T/PV on mfma_f32_32x32x16_bf16; C/D: col=lane&31, row=(reg&3)+8*(reg>>2)+4*half.
__global__ __launch_bounds__(256, 4)
void attn_kernel(const float* __restrict__ Qg, const bf16* __restrict__ Kc,
                 const bf16* __restrict__ Vtg, const u64* __restrict__ MB,
                 bf16* __restrict__ heads)
{
    __shared__ bf16 Ks[128 * LDT];                // k-rows permuted within 32-groups
    __shared__ bf16 Vs[64 * LDTV];                // [d][s-in-tile 0..127]

    const int tid  = threadIdx.x;
    const int lane = tid & 63;
    const int wave = tid >> 6;
    const int l31  = lane & 31;
    const int half = lane >> 5;

    const int blk = blockIdx.x;                   // ((b*4)+qt)*16 + h
    const int h   = blk & 15;
    const int qt  = (blk >> 4) & 3;
    const int b   = blk >> 6;
    const int qw  = qt * 128 + wave * 32;         // wave's q base; q = qw + l31

    // ---- Q B-frags: lane holds Q[qw+l31][ds*16 + half*8 + j] * 0.125*log2e ----
    constexpr float QSCL = 0.125f * 1.44269504088896340736f;
    bf16x8 aq[4];
    {
        const float* qb = Qg + ((size_t)((b * S + qw + l31) * H + h)) * Dh + half * 8;
#pragma unroll
        for (int ds = 0; ds < 4; ++ds) {
            floatx4 f0 = *(const floatx4*)(qb + ds * 16);
            floatx4 f1 = *(const floatx4*)(qb + ds * 16 + 4);
#pragma unroll
            for (int j = 0; j < 4; ++j) {
                aq[ds][j]     = (bf16)(f0[j] * QSCL);
                aq[ds][j + 4] = (bf16)(f1[j] * QSCL);
            }
        }
    }

    float rsum = 0.f;
    floatx16 O[2];                                // O^T[d = dt*32 + crow][q = l31]
#pragma unroll
    for (int dt = 0; dt < 2; ++dt)
#pragma unroll
        for (int i = 0; i < 16; ++i) O[dt][i] = 0.f;

    const u64* mbrow = MB + ((size_t)b * S + qw + l31) * 8;   // per-lane q row
    const bf16* vplane = Vtg + (size_t)(b * 16 + h) * 64 * S;

    // R11-exact staging geometry: sr = tid>>2 (0..63), sc = (tid&3)*16.
    const int sr = tid >> 2, sc_ = (tid & 3) * 16;
    // K row permutation within each 32-group (swap bits 2<->3).
    const int kperm = (sr & 0x33) | ((sr & 4) << 1) | ((sr & 8) >> 1);

    // K sources: rows kperm (pass A) and 64+kperm (pass B) of each 128-k tile.
    const bf16* ksrcA = Kc + ((size_t)((b * S + kperm) * H + h)) * Dh + sc_;
    const bf16* ksrcB = ksrcA + (size_t)64 * H * Dh;
    // V sources: d-row sr, s-cols sc (pass A) and 64+sc (pass B).
    const bf16* vsrcA = vplane + (size_t)sr * S + sc_;
    const bf16* vsrcB = vsrcA + 64;
    const size_t kstep = (size_t)128 * H * Dh;    // Kc elements per 128-k tile

    // ---- prologue: tile 0 into regs (single def-site, no conditionals) ----
    ushort8 ka0 = *(const ushort8*)ksrcA;
    ushort8 ka1 = *(const ushort8*)(ksrcA + 8);
    ushort8 kb0 = *(const ushort8*)ksrcB;
    ushort8 kb1 = *(const ushort8*)(ksrcB + 8);
    ushort8 va0 = *(const ushort8*)vsrcA;
    ushort8 va1 = *(const ushort8*)(vsrcA + 8);
    ushort8 vb0 = *(const ushort8*)vsrcB;
    ushort8 vb1 = *(const ushort8*)(vsrcB + 8);
    u64 mregA = mbrow[0];
    u64 mregB = mbrow[1];

    for (int it = 0; it < 4; ++it) {
        __syncthreads();                          // prev tile's LDS reads done
        *(ushort8*)&Ks[sr * LDT + sc_]             = ka0;   // pass A: rows 0..63
        *(ushort8*)&Ks[sr * LDT + sc_ + 8]         = ka1;
        *(ushort8*)&Ks[(64 + sr) * LDT + sc_]      = kb0;   // pass B: rows 64..127
        *(ushort8*)&Ks[(64 + sr) * LDT + sc_ + 8]  = kb1;
        *(ushort8*)&Vs[sr * LDTV + sc_]            = va0;   // pass A: s 0..63
        *(ushort8*)&Vs[sr * LDTV + sc_ + 8]        = va1;
        *(ushort8*)&Vs[sr * LDTV + 64 + sc_]       = vb0;   // pass B: s 64..127
        *(ushort8*)&Vs[sr * LDTV + 64 + sc_ + 8]   = vb1;
        const u64 mA = mregA, mB = mregB;
        __syncthreads();                          // LDS visible

        // ---- unconditional prefetch of tile (it+1)&3 (wraps; branch-free) ----
        {
            const int in_ = (it + 1) & 3;
            const bf16* kA = ksrcA + (size_t)in_ * kstep;
            const bf16* kB = ksrcB + (size_t)in_ * kstep;
            const bf16* vA = vsrcA + in_ * 128;
            const bf16* vB = vsrcB + in_ * 128;
            ka0 = *(const ushort8*)kA;
            ka1 = *(const ushort8*)(kA + 8);
            kb0 = *(const ushort8*)kB;
            kb1 = *(const ushort8*)(kB + 8);
            va0 = *(const ushort8*)vA;
            va1 = *(const ushort8*)(vA + 8);
            vb0 = *(const ushort8*)vB;
            vb1 = *(const ushort8*)(vB + 8);
            mregA = mbrow[in_ * 2];
            mregB = mbrow[in_ * 2 + 1];
        }

        // ---- S^T per 32-k tile t (0..3): C reg r holds
        // k = it*128 + t*32 + (r>>3)*16 + half*8 + (r&7) ----
        bf16x8 pB[8];                             // P^T B-operands, 16-k slice each
#pragma unroll
        for (int t = 0; t < 4; ++t) {
            floatx16 acc;
#pragma unroll
            for (int i = 0; i < 16; ++i) acc[i] = 0.f;
#pragma unroll
            for (int ds = 0; ds < 4; ++ds) {
                bf16x8 ak = *(const bf16x8*)&Ks[(t * 32 + l31) * LDT + ds * 16 + half * 8];
                acc = MFMA32x32(ak, aq[ds], acc);
            }
            const u64 mw = (t < 2) ? mA : mB;
            const unsigned w = (unsigned)(mw >> ((t & 1) * 32 + half * 8));
#pragma unroll
            for (int r = 0; r < 16; ++r) {
                float e = fexp2(acc[r]);                    // v_exp_f32
                int sx = sbfe1(w, (r >> 3) * 16 + (r & 7)); // 0 or -1
                float p = __uint_as_float(__float_as_uint(e) & (unsigned)sx);
                rsum += p;
                pB[t * 2 + (r >> 3)][r & 7] = (bf16)p;
            }
        }

        // ---- O^T += V^T · P^T : A = Vs rows (natural), B = pB k-slices ----
#pragma unroll
        for (int dt = 0; dt < 2; ++dt)
#pragma unroll
            for (int s_ = 0; s_ < 8; ++s_) {
                bf16x8 av = *(const bf16x8*)&Vs[(dt * 32 + l31) * LDTV + s_ * 16 + half * 8];
                O[dt] = MFMA32x32(av, pB[s_], O[dt]);
            }
    }

    // ---- reduce row sums: lanes l and l+32 share q = l31, disjoint k halves ----
    rsum += __shfl_xor(rsum, 32, 64);
    const float inv = (rsum > 0.f) ? (1.f / rsum) : 0.f;

    // ---- epilogue: O^T[d][q] -> heads[b][q][h][d]; d = dt*32 + g*8 + half*4 + j ----
    bf16* hrow = heads + ((size_t)((b * S + qw + l31) * H + h)) * Dh;
#pragma unroll
    for (int dt = 0; dt < 2; ++dt) {
#pragma unroll
        for (int g = 0; g < 4; ++g) {
            bf16x4 h4;
#pragma unroll
            for (int j = 0; j < 4; ++j) h4[j] = (bf16)(O[dt][g * 4 + j] * inv);
            *(bf16x4*)&hrow[dt * 32 + g * 8 + half * 4] = h4;
        }
    }
}

// Projection: heads (8192x1024) @ Wt^T. 128x128 tile, BK=128 (8 K-steps),
// LDS linear for global_load_lds with PRE-SWIZZLED global source (rule 21):
// 16B unit (row, u) stored at phys u ^ (row&7); reads re-apply the XOR.
__global__ __launch_bounds__(256)
void proj_kernel(const bf16* __restrict__ A, const bf16* __restrict__ Wt,
                 float* __restrict__ out)
{
    __shared__ bf16 As[128 * 128];                // 32 KB, linear
    __shared__ bf16 Ws[128 * 128];                // 32 KB, linear

    const int tid  = threadIdx.x;
    const int lane = tid & 63;
    const int wave = tid >> 6;
    const int l15  = lane & 15;
    const int quad = lane >> 4;

    const int nb = blockIdx.x & 7;
    const int mb = blockIdx.x >> 3;
    const int mbase = mb * 128, nbase = nb * 128;
    const int wm = (wave & 1) * 64, wn = (wave >> 1) * 64;

    const int srow4 = lane >> 4;                  // 0..3
    const int su    = lane & 15;

    floatx4 O[4][4];
#pragma unroll
    for (int mt = 0; mt < 4; ++mt)
#pragma unroll
        for (int nt = 0; nt < 4; ++nt) O[mt][nt] = floatx4{0.f, 0.f, 0.f, 0.f};

    for (int kt = 0; kt < 8; ++kt) {
        const int kb = kt * 128;
        if (kt) __syncthreads();                  // prev compute done; LDS free

#pragma unroll
        for (int j = 0; j < 8; ++j) {
            const int rowbase = wave * 32 + j * 4;
            const int cu = (su ^ ((rowbase + srow4) & 7)) * 8;
            gload16(A  + (size_t)(mbase + rowbase + srow4) * D + kb + cu,
                    As + rowbase * 128, lane);
            gload16(Wt + (size_t)(nbase + rowbase + srow4) * D + kb + cu,
                    Ws + rowbase * 128, lane);
        }

        __syncthreads();                          // vmcnt drained -> LDS visible

#pragma unroll
        for (int c = 0; c < 4; ++c) {
            const int uc = c * 4 + quad;          // logical 16B unit (K chunk c)
            bf16x8 fa[4];
#pragma unroll
            for (int mt = 0; mt < 4; ++mt) {
                const int row = wm + mt * 16 + l15;
                fa[mt] = *(const bf16x8*)&As[row * 128 + ((uc ^ (row & 7)) * 8)];
            }
#pragma unroll
            for (int nt = 0; nt < 4; ++nt) {
                const int row = wn + nt * 16 + l15;
                bf16x8 fb = *(const bf16x8*)&Ws[row * 128 + ((uc ^ (row & 7)) * 8)];
#pragma unroll
                for (int mt = 0; mt < 4; ++mt)
                    O[mt][nt] = MFMA32(fa[mt], fb, O[mt][nt]);
            }
        }
    }

#pragma unroll
    for (int mt = 0; mt < 4; ++mt) {
#pragma unroll
        for (int nt = 0; nt < 4; ++nt) {
#pragma unroll
            for (int reg = 0; reg < 4; ++reg) {
                const int m = mbase + wm + mt * 16 + quad * 4 + reg;
                const int n = nbase + wn + nt * 16 + l15;
                out[(size_t)m * D + n] = O[mt][nt][reg];
            }
        }
    }
}

extern "C" void kernel_launch(void* const* d_in, const int* in_sizes, int n_in,
                              void* d_out, int out_size, void* d_ws, size_t ws_size,
                              hipStream_t stream)
{
    const float* pre_q = (const float*)d_in[0];
    const float* pre_v = (const float*)d_in[1];
    const float* pre_k = (const float*)d_in[2];
    const int*   mask  = (const int*)d_in[3];
    const float* Wg    = (const float*)d_in[4];
    float* out = (float*)d_out;

    bf16* Kc    = (bf16*)d_ws;
    bf16* Vt    = Kc + QN;
    bf16* Wt    = Vt + QN;
    bf16* heads = Wt + WN;
    u64*  MB    = (u64*)(heads + QN);

    prep_kernel<<<4352, 256, 0, stream>>>(pre_k, pre_v, Wg, mask, Kc, Vt, Wt, MB);
    attn_kernel<<<1024, 256, 0, stream>>>(pre_q, Kc, Vt, MB, heads);
    proj_kernel<<<512, 256, 0, stream>>>(heads, Wt, out);
}